// Round 3
// baseline (3600.705 us; speedup 1.0000x reference)
//
#include <hip/hip_runtime.h>

// psRNN round 10: 2-group time-multiplex to HIDE the sync chain.
// r9 post-mortem: round latency 4.03us == r7's 4.23us despite single-XCD data
// and half the work => the serial chain (publish->drain->LLC flag->poll->L2
// load->MFMA->combine) is a fixed ~10k-cy cost per sync; r7 won only by
// amortizing 2 steps over it (W^2). New approach: W frags are batch-agnostic,
// so each XCD runs TWO independent batch-groups (4+4) interleaved on the same
// waves. While G0's flag/poll propagates, the wave computes G1's MFMA and
// vice versa -- sync latency AND straggler jitter absorbed by ~1250cy of
// other-group compute on each side. MFMA count doubles (M-tile 1/4 used) but
// MFMA was only 16% busy in r7. Loads: issue-early inline asm (no waitcnt),
// drained by the publish's existing vmcnt(0) one phase later. LDS: ybuf/ubuf
// double-buffered per group; raw s_barrier with lgkmcnt-only drain keeps
// prefetches in flight (__syncthreads would vmcnt(0)-drain and serialize).
// Flags: r7/r9-proven agent-scope LLC atomics. Data: sc0 XCD-L2.
// Predicted: pair ~4.2k cy -> ~900us, MfmaUtil ~25%, no outlier dispatches.

typedef _Float16 half_t;
typedef _Float16 half8 __attribute__((ext_vector_type(8)));
typedef float f32x4 __attribute__((ext_vector_type(4)));

#define NHID 2048
#define NOUT 64
#define N_ROUNDS 512
#define STU 8192   // halfs per (buf, rep, grp): [4 batch][2048 n]

#define MFMA16(A, B, C) __builtin_amdgcn_mfma_f32_16x16x32_f16(A, B, C, 0, 0, 0)

// ws layout (bytes):
//   [0, 8192)       : flags uint[2][8][128]  (agent/LLC, monotonic)
//   [16384, 16416)  : roster uint[8]
//   [1M, 1M+768K)   : St  half[3][8][2][STU]    (rotating state bufs, sc0)
//   [2M, 2M+256K)   : StFinal half[8][2][STU]   (final state, sc1/LLC)

__device__ __forceinline__ half8 cvt8(float4 lo, float4 hi) {
  half8 h;
  h[0] = (half_t)lo.x; h[1] = (half_t)lo.y; h[2] = (half_t)lo.z; h[3] = (half_t)lo.w;
  h[4] = (half_t)hi.x; h[5] = (half_t)hi.y; h[6] = (half_t)hi.z; h[7] = (half_t)hi.w;
  return h;
}

__global__ void psrnn_init_kernel(unsigned* flags, unsigned* roster, uint4* st) {
  int g = blockIdx.x * blockDim.x + threadIdx.x;  // 16384 threads
  uint4 v; v.x = 0x3C003C00u; v.y = 0x3C003C00u; v.z = 0x3C003C00u; v.w = 0x3C003C00u;
  st[g] = v;  // buf0, all reps/groups := fp16 1.0 (16384 uint4 = 256KB)
  if (g < 2048) flags[g] = 1u;
  else if (g < 2056) roster[g - 2048] = 0u;
}

// ---- issue 16 dwordx4 sc0 loads, NO waitcnt (drained later by vmcnt(0))
#define ISSUE16(D, P)                                                     \
    asm volatile(                                                         \
        "global_load_dwordx4 %0, %16, off sc0\n\t"                        \
        "global_load_dwordx4 %1, %16, off offset:64 sc0\n\t"              \
        "global_load_dwordx4 %2, %16, off offset:128 sc0\n\t"             \
        "global_load_dwordx4 %3, %16, off offset:192 sc0\n\t"             \
        "global_load_dwordx4 %4, %16, off offset:256 sc0\n\t"             \
        "global_load_dwordx4 %5, %16, off offset:320 sc0\n\t"             \
        "global_load_dwordx4 %6, %16, off offset:384 sc0\n\t"             \
        "global_load_dwordx4 %7, %16, off offset:448 sc0\n\t"             \
        "global_load_dwordx4 %8, %16, off offset:512 sc0\n\t"             \
        "global_load_dwordx4 %9, %16, off offset:576 sc0\n\t"             \
        "global_load_dwordx4 %10, %16, off offset:640 sc0\n\t"            \
        "global_load_dwordx4 %11, %16, off offset:704 sc0\n\t"            \
        "global_load_dwordx4 %12, %16, off offset:768 sc0\n\t"            \
        "global_load_dwordx4 %13, %16, off offset:832 sc0\n\t"            \
        "global_load_dwordx4 %14, %16, off offset:896 sc0\n\t"            \
        "global_load_dwordx4 %15, %16, off offset:960 sc0"                \
        : "=&v"(D[0]), "=&v"(D[1]), "=&v"(D[2]), "=&v"(D[3]),             \
          "=&v"(D[4]), "=&v"(D[5]), "=&v"(D[6]), "=&v"(D[7]),             \
          "=&v"(D[8]), "=&v"(D[9]), "=&v"(D[10]), "=&v"(D[11]),           \
          "=&v"(D[12]), "=&v"(D[13]), "=&v"(D[14]), "=&v"(D[15])          \
        : "v"(P) : "memory")

#define WAITV()                                              \
    do {                                                     \
      asm volatile("s_waitcnt vmcnt(0)" ::: "memory");       \
      __builtin_amdgcn_sched_barrier(0);                     \
    } while (0)

// raw barrier: drain own LDS ops only; vmem prefetches stay in flight
#define BARRIER()                                            \
    do {                                                     \
      __builtin_amdgcn_sched_barrier(0);                     \
      asm volatile("s_waitcnt lgkmcnt(0)" ::: "memory");     \
      __builtin_amdgcn_s_barrier();                          \
      __builtin_amdgcn_sched_barrier(0);                     \
    } while (0)

__global__ __launch_bounds__(256, 1) void psrnn_main_kernel(
    const float* __restrict__ x,      // [512][64][64]
    const float* __restrict__ Wi_w,   // [2048][64]
    const float* __restrict__ Wi_b,   // [2048]
    const float* __restrict__ Wh_w,   // [2048][2048]
    const float* __restrict__ Av,     // [2048]
    const float* __restrict__ Om,     // [2048]
    unsigned* __restrict__ flags,
    unsigned* __restrict__ roster,
    half_t* __restrict__ St,          // rotating bufs (XCD-local, sc0)
    half_t* __restrict__ StFinal)     // final state (sc1/LLC)
{
  extern __shared__ char lds_force[];     // dyn pad: forces 1 block/CU
  __shared__ float ybuf[2][4][4][16][5];  // [grp][wave][nt][row16][batch4+pad]
  __shared__ float ubuf[2][4][16][5];     // [grp][nt][row16][batch4+pad]
  __shared__ unsigned slot_sh;
  (void)lds_force;

  const int tid = threadIdx.x, w = tid >> 6, lane = tid & 63;
  const int lm = lane & 15, kg = lane >> 4, lb2 = lm & 3;

  unsigned xcd;
  asm volatile("s_getreg_b32 %0, hwreg(HW_REG_XCC_ID)" : "=s"(xcd));
  const int rep = (int)(xcd & 7u);
  if (tid == 0) slot_sh = atomicAdd(&roster[rep], 1u) & 31u;
  __syncthreads();
  const int slot = (int)slot_sh;
  const int n0 = slot * 64, b0 = rep * 8;

  // ---- W B-frags: rows n0 + nt*16 + lm, K = w*512 + c*32 + kg*8 ..+8
  half8 wb[4][16];
#pragma unroll
  for (int nt = 0; nt < 4; ++nt)
#pragma unroll
    for (int c = 0; c < 16; ++c) {
      const float* p = Wh_w + (size_t)(n0 + nt * 16 + lm) * NHID + (w * 512 + c * 32 + kg * 8);
      wb[nt][c] = cvt8(*(const float4*)p, *(const float4*)(p + 4));
    }
  // Wi B-frags for row tile w: rows n0 + w*16 + lm, K = 0..64
  half8 wi0, wi1;
  {
    const float* p = Wi_w + (size_t)(n0 + w * 16 + lm) * 64 + kg * 8;
    wi0 = cvt8(*(const float4*)p, *(const float4*)(p + 4));
    wi1 = cvt8(*(const float4*)(p + 32), *(const float4*)(p + 36));
  }

  // ---- combiner: thread owns (group-batch bt=w, local row rr)
  const int rr = tid & 63, ng = n0 + rr;
  const float cA = Av[ng], cOm = Om[ng], cB = Wi_b[ng];
  float cpr0, cpr1;

  unsigned* const poll0 = flags + (0 * 8 + rep) * 128 + 32 * w + (lane & 31);
  unsigned* const poll1 = flags + (1 * 8 + rep) * 128 + 32 * w + (lane & 31);
  unsigned* const myf0  = flags + (0 * 8 + rep) * 128 + slot * 4 + w;
  unsigned* const myf1  = flags + (1 * 8 + rep) * 128 + slot * 4 + w;

#define POLL(P, TGT)                                                            \
  do {                                                                          \
    unsigned v_ = __hip_atomic_load(P, __ATOMIC_RELAXED, __HIP_MEMORY_SCOPE_AGENT); \
    while (!__all((int)(v_ >= (unsigned)(TGT))))                                \
      v_ = __hip_atomic_load(P, __ATOMIC_RELAXED, __HIP_MEMORY_SCOPE_AGENT);    \
  } while (0)

#define UMFMA(G, X0, X1, X2, X3)                                  \
  do {                                                            \
    f32x4 au = {0.f, 0.f, 0.f, 0.f};                              \
    au = MFMA16(cvt8(X0, X1), wi0, au);                           \
    au = MFMA16(cvt8(X2, X3), wi1, au);                           \
    if (kg == 0) {                                                \
      _Pragma("unroll")                                           \
      for (int r = 0; r < 4; ++r) ubuf[G][w][lm][r] = au[r];      \
    }                                                             \
  } while (0)

#define GEMM(SR, G)                                                       \
  do {                                                                    \
    f32x4 a0 = {0.f,0.f,0.f,0.f}, a1 = {0.f,0.f,0.f,0.f};                 \
    f32x4 a2 = {0.f,0.f,0.f,0.f}, a3 = {0.f,0.f,0.f,0.f};                 \
    _Pragma("unroll")                                                     \
    for (int c = 0; c < 16; ++c) {                                        \
      half8 sf = __builtin_bit_cast(half8, SR[c]);                        \
      a0 = MFMA16(sf, wb[0][c], a0);                                      \
      a1 = MFMA16(sf, wb[1][c], a1);                                      \
      a2 = MFMA16(sf, wb[2][c], a2);                                      \
      a3 = MFMA16(sf, wb[3][c], a3);                                      \
    }                                                                     \
    if (kg == 0) {                                                        \
      _Pragma("unroll")                                                   \
      for (int r = 0; r < 4; ++r) {                                       \
        ybuf[G][w][0][lm][r] = a0[r];                                     \
        ybuf[G][w][1][lm][r] = a1[r];                                     \
        ybuf[G][w][2][lm][r] = a2[r];                                     \
        ybuf[G][w][3][lm][r] = a3[r];                                     \
      }                                                                   \
    }                                                                     \
  } while (0)

// combine + publish + flag for group G (bt == w)
#define COMBINE(G, CPR, MYF)                                                     \
  do {                                                                           \
    const int nt_ = rr >> 4, lm_ = rr & 15;                                      \
    const float y_ = ybuf[G][0][nt_][lm_][w] + ybuf[G][1][nt_][lm_][w] +         \
                     ybuf[G][2][nt_][lm_][w] + ybuf[G][3][nt_][lm_][w];          \
    const float u_ = ubuf[G][nt_][lm_][w] + cB;                                  \
    const float s2_ = CPR + y_;                                                  \
    CPR = cA * __cosf(cOm * s2_ + u_);                                           \
    unsigned hv_ = (unsigned)__builtin_bit_cast(unsigned short, (half_t)s2_);    \
    const half_t* wp_ = St + (size_t)((bW * 8 + rep) * 2 + (G)) * STU +          \
                        w * NHID + ng;                                           \
    asm volatile("global_store_short %0, %1, off sc0" :: "v"(wp_), "v"(hv_) : "memory"); \
    if (k == N_ROUNDS - 1) {                                                     \
      const half_t* fp_ = StFinal + (size_t)(rep * 2 + (G)) * STU + w * NHID + ng; \
      asm volatile("global_store_short %0, %1, off sc1" :: "v"(fp_), "v"(hv_) : "memory"); \
    }                                                                            \
    asm volatile("s_waitcnt vmcnt(0)" ::: "memory");                             \
    if (lane == 0)                                                               \
      __hip_atomic_store(MYF, (unsigned)(k + 2), __ATOMIC_RELAXED,               \
                         __HIP_MEMORY_SCOPE_AGENT);                              \
  } while (0)

  // ---- preloop: u_0 both groups -> cpr; prefetch x_1; issue SrA (buf0, G0)
  {
    const float* xp0 = x + (size_t)(b0 + lb2) * 64;
    const float* xp1 = x + (size_t)(b0 + 4 + lb2) * 64;
    float4 a0 = *(const float4*)(xp0 + kg * 8), a1 = *(const float4*)(xp0 + kg * 8 + 4);
    float4 a2 = *(const float4*)(xp0 + 32 + kg * 8), a3 = *(const float4*)(xp0 + 36 + kg * 8);
    UMFMA(0, a0, a1, a2, a3);
    a0 = *(const float4*)(xp1 + kg * 8);  a1 = *(const float4*)(xp1 + kg * 8 + 4);
    a2 = *(const float4*)(xp1 + 32 + kg * 8); a3 = *(const float4*)(xp1 + 36 + kg * 8);
    UMFMA(1, a0, a1, a2, a3);
  }
  __syncthreads();
  {
    const int nt_ = rr >> 4, lm_ = rr & 15;
    cpr0 = cA * __cosf(cOm * 1.0f + ubuf[0][nt_][lm_][w] + cB);
    cpr1 = cA * __cosf(cOm * 1.0f + ubuf[1][nt_][lm_][w] + cB);
  }
  __syncthreads();

  float4 xr00, xr01, xr02, xr03;  // x_{k+1} for G0
  float4 xr10, xr11, xr12, xr13;  // x_{k+1} for G1
  {
    const float* xp0 = x + ((size_t)1 * 64 + b0 + lb2) * 64;
    const float* xp1 = x + ((size_t)1 * 64 + b0 + 4 + lb2) * 64;
    xr00 = *(const float4*)(xp0 + kg * 8);      xr01 = *(const float4*)(xp0 + kg * 8 + 4);
    xr02 = *(const float4*)(xp0 + 32 + kg * 8); xr03 = *(const float4*)(xp0 + 36 + kg * 8);
    xr10 = *(const float4*)(xp1 + kg * 8);      xr11 = *(const float4*)(xp1 + kg * 8 + 4);
    xr12 = *(const float4*)(xp1 + 32 + kg * 8); xr13 = *(const float4*)(xp1 + 36 + kg * 8);
  }

  float4 SrA[16], SrB[16];
  {
    const half_t* pA0 = St + (size_t)((0 * 8 + rep) * 2 + 0) * STU +
                        lb2 * NHID + (w * 512 + kg * 8);
    ISSUE16(SrA, pA0);
  }

  int bR = 0;
  for (int k = 0; k < N_ROUNDS; ++k) {
    const int bW = (bR == 2) ? 0 : bR + 1;

    // ---- [A] MFMA G0 (SrA prefetched; already drained by prev combine)
    WAITV();
    GEMM(SrA, 0);

    // ---- [B] u_{k+1} G0; poll G1 (s_k^G1 ready); issue SrB
    UMFMA(0, xr00, xr01, xr02, xr03);
    POLL(poll1, k + 1);
    {
      const half_t* pB = St + (size_t)((bR * 8 + rep) * 2 + 1) * STU +
                         lb2 * NHID + (w * 512 + kg * 8);
      ISSUE16(SrB, pB);
    }

    // ---- [C] combine+publish G0 (SrB latency hides under this)
    BARRIER();
    COMBINE(0, cpr0, myf0);
    {
      int t = k + 2; if (t > 511) t = 511;
      const float* xp = x + ((size_t)t * 64 + b0 + lb2) * 64;   // G0's x_{k+2}
      xr00 = *(const float4*)(xp + kg * 8);      xr01 = *(const float4*)(xp + kg * 8 + 4);
      xr02 = *(const float4*)(xp + 32 + kg * 8); xr03 = *(const float4*)(xp + 36 + kg * 8);
    }

    // ---- [D] MFMA G1
    WAITV();
    GEMM(SrB, 1);

    // ---- [E] u_{k+1} G1; poll G0 (s_{k+1}^G0 ready); issue SrA for k+1
    UMFMA(1, xr10, xr11, xr12, xr13);
    POLL(poll0, k + 2);
    {
      const half_t* pA = St + (size_t)((bW * 8 + rep) * 2 + 0) * STU +
                         lb2 * NHID + (w * 512 + kg * 8);
      ISSUE16(SrA, pA);
    }

    // ---- [F] combine+publish G1 (SrA latency hides under this)
    BARRIER();
    COMBINE(1, cpr1, myf1);
    {
      int t = k + 2; if (t > 511) t = 511;
      const float* xp = x + ((size_t)t * 64 + b0 + 4 + lb2) * 64; // G1's x_{k+2}
      xr10 = *(const float4*)(xp + kg * 8);      xr11 = *(const float4*)(xp + kg * 8 + 4);
      xr12 = *(const float4*)(xp + 32 + kg * 8); xr13 = *(const float4*)(xp + 36 + kg * 8);
    }

    bR = bW;
  }
#undef POLL
#undef UMFMA
#undef GEMM
#undef COMBINE
}

__global__ __launch_bounds__(256) void psrnn_readout_kernel(
    const float* __restrict__ Wr_w,     // [64][2048]
    const float* __restrict__ Wr_b,     // [64]
    const half_t* __restrict__ StFinal, // [8][8][2048] (rep-major, batch-linear)
    float* __restrict__ out)            // [64][64]
{
  const int tid = threadIdx.x, v = tid >> 6, lane = tid & 63;
  const int lm = lane & 15, kg = lane >> 4, lb = lm & 7;
  const int rep = blockIdx.x;  // 8 blocks
  const half_t* sb = StFinal + (size_t)rep * 16384;

  f32x4 acc = {0.f, 0.f, 0.f, 0.f};
  for (int cg = 0; cg < 64; ++cg) {
    half8 a = *(const half8*)(sb + (size_t)lb * NHID + cg * 32 + kg * 8);
    const float* p = Wr_w + (size_t)(v * 16 + lm) * NHID + cg * 32 + kg * 8;
    half8 b = cvt8(*(const float4*)p, *(const float4*)(p + 4));
    acc = MFMA16(a, b, acc);
  }
  if (kg < 2)
#pragma unroll
    for (int r = 0; r < 4; ++r)
      out[(rep * 8 + kg * 4 + r) * NOUT + v * 16 + lm] = acc[r] + Wr_b[v * 16 + lm];
}

extern "C" void kernel_launch(void* const* d_in, const int* in_sizes, int n_in,
                              void* d_out, int out_size, void* d_ws, size_t ws_size,
                              hipStream_t stream) {
  const float* x    = (const float*)d_in[0];
  const float* Wi_w = (const float*)d_in[1];
  const float* Wi_b = (const float*)d_in[2];
  const float* Wh_w = (const float*)d_in[3];
  const float* Av   = (const float*)d_in[4];
  const float* Om   = (const float*)d_in[5];
  const float* Wr_w = (const float*)d_in[6];
  const float* Wr_b = (const float*)d_in[7];

  unsigned* flags   = (unsigned*)d_ws;
  unsigned* roster  = (unsigned*)((char*)d_ws + 16384);
  half_t*   St      = (half_t*)((char*)d_ws + (1u << 20));
  half_t*   StFinal = (half_t*)((char*)d_ws + (2u << 20));

  psrnn_init_kernel<<<64, 256, 0, stream>>>(flags, roster, (uint4*)St);
  psrnn_main_kernel<<<256, 256, 69632, stream>>>(x, Wi_w, Wi_b, Wh_w, Av, Om,
                                                 flags, roster, St, StFinal);
  psrnn_readout_kernel<<<8, 256, 0, stream>>>(Wr_w, Wr_b, StFinal, (float*)d_out);
}

// Round 4
// 2039.966 us; speedup vs baseline: 1.7651x; 1.7651x over previous
//
#include <hip/hip_runtime.h>

// psRNN round 11: r9 + L2-scope flag handshake experiment (single variable).
// r10 post-mortem: software-interleaving two sync chains on the same waves
// serialized fully (pair 7.03us = 2x r9's 4.03; polls block the wave with
// only ~650cy of foreign compute to hide under). >2 steps/sync is
// algebraically impossible (needs un-broadcast c_{t+1}), W+W^2 doesn't fit a
// single XCD's regfile, so the only lever left is chain latency itself.
// r8 forensics: its round was 10.6us = exactly 64 sc0-spins x ~400cy => the
// sc0 flag spin NEVER saw the update (consumer L1 served stale; data only
// stayed fresh via 64KB/round capacity eviction of the 32KB L1). Flags have
// therefore been paying LLC RTT + 1024-wave agent poll traffic every round.
// This round: producers publish flags BOTH ways (raw sc0 store -> shared XCD
// L2, agent atomic -> LLC backup); consumers ALTERNATE {sc0 nt load} (nt
// should bypass stale L1, hit shared L2) and {agent load}, break on either.
// Fail-safe: if nt doesn't bypass L1, agent leg still detects (~r9 perf).
// Predicted: 900-1400us if L2 handshake works (MfmaUtil 15-25%); <=2.2ms if
// not. Decides next round's direction (wave-decoupled design vs r7+canary).

typedef _Float16 half_t;
typedef _Float16 half8 __attribute__((ext_vector_type(8)));
typedef float f32x4 __attribute__((ext_vector_type(4)));

#define NHID 2048
#define NOUT 64
#define N_ROUNDS 512
#define ST_UNIT 16384   // halfs per (buf,rep): [8 batch][2048 n]

#define MFMA16(A, B, C) __builtin_amdgcn_mfma_f32_16x16x32_f16(A, B, C, 0, 0, 0)

// ws layout (bytes):
//   [0, 4096)        : flagsL uint[8][128]  (sc0 / XCD-L2 copy, monotonic)
//   [8192, 12288)    : flagsG uint[8][128]  (agent / LLC copy, monotonic)
//   [16384, 16416)   : roster uint[8]       (per-XCD block counter)
//   [1M, 1M+768K)    : St  half[3][8][ST_UNIT]   (rotating state bufs, sc0)
//   [2M, 2M+256K)    : StFinal half[8][ST_UNIT]  (final state, sc1/LLC)

__device__ __forceinline__ half8 cvt8(float4 lo, float4 hi) {
  half8 h;
  h[0] = (half_t)lo.x; h[1] = (half_t)lo.y; h[2] = (half_t)lo.z; h[3] = (half_t)lo.w;
  h[4] = (half_t)hi.x; h[5] = (half_t)hi.y; h[6] = (half_t)hi.z; h[7] = (half_t)hi.w;
  return h;
}

__global__ void psrnn_init_kernel(unsigned* flagsL, unsigned* flagsG,
                                  unsigned* roster, uint4* st) {
  int g = blockIdx.x * blockDim.x + threadIdx.x;  // 16384 threads
  uint4 v; v.x = 0x3C003C00u; v.y = 0x3C003C00u; v.z = 0x3C003C00u; v.w = 0x3C003C00u;
  st[g] = v;  // buf0, all 8 reps := fp16 1.0
  if (g < 1024) { flagsL[g] = 1u; flagsG[g] = 1u; }
  else if (g < 1032) roster[g - 1024] = 0u;
}

__global__ __launch_bounds__(256, 1) void psrnn_main_kernel(
    const float* __restrict__ x,      // [512][64][64]
    const float* __restrict__ Wi_w,   // [2048][64]
    const float* __restrict__ Wi_b,   // [2048]
    const float* __restrict__ Wh_w,   // [2048][2048]
    const float* __restrict__ Av,     // [2048]
    const float* __restrict__ Om,     // [2048]
    unsigned* __restrict__ flagsL,
    unsigned* __restrict__ flagsG,
    unsigned* __restrict__ roster,
    half_t* __restrict__ St,          // rotating bufs (XCD-local, sc0)
    half_t* __restrict__ StFinal)     // final state (sc1/LLC)
{
  extern __shared__ char lds_force[];        // +60KB dyn: forces 1 block/CU
  __shared__ float ybuf[2][4][4][16][9];     // [par][wave][nt][row16][batch8+pad]
  __shared__ float ubuf[2][4][16][9];        // [par][nt][row16][batch8+pad]
  __shared__ unsigned slot_sh;
  (void)lds_force;

  const int tid = threadIdx.x, w = tid >> 6, lane = tid & 63;
  const int lm = lane & 15, kg = lane >> 4, lb = lm & 7;

  unsigned xcd;
  asm volatile("s_getreg_b32 %0, hwreg(HW_REG_XCC_ID)" : "=s"(xcd));
  const int rep = (int)(xcd & 7u);
  if (tid == 0) slot_sh = atomicAdd(&roster[rep], 1u) & 31u;
  __syncthreads();
  const int slot = (int)slot_sh;
  const int n0 = slot * 64, b0 = rep * 8;

  // ---- W B-frags: rows n0 + nt*16 + lm, K = w*512 + c*32 + kg*8 .. +8
  half8 wb[4][16];
#pragma unroll
  for (int nt = 0; nt < 4; ++nt)
#pragma unroll
    for (int c = 0; c < 16; ++c) {
      const float* p = Wh_w + (size_t)(n0 + nt * 16 + lm) * NHID + (w * 512 + c * 32 + kg * 8);
      wb[nt][c] = cvt8(*(const float4*)p, *(const float4*)(p + 4));
    }
  // Wi B-frags for u-tile nt=w: rows n0 + w*16 + lm, K = 0..64
  half8 wi0, wi1;
  {
    const float* p = Wi_w + (size_t)(n0 + w * 16 + lm) * 64 + kg * 8;
    wi0 = cvt8(*(const float4*)p, *(const float4*)(p + 4));
    wi1 = cvt8(*(const float4*)(p + 32), *(const float4*)(p + 36));
  }

  // ---- combiner constants: thread owns (batch m, local rows r0, r0+1)
  const int m = tid >> 5;            // 0..7
  const int r0 = (tid & 31) * 2;     // 0..62
  float cA2[2], cOm2[2], cB2[2];
#pragma unroll
  for (int j = 0; j < 2; ++j) {
    const int ng = n0 + r0 + j;
    cA2[j] = Av[ng]; cOm2[j] = Om[ng]; cB2[j] = Wi_b[ng];
  }
  float cpr[2];

  unsigned* const pollL = flagsL + rep * 128 + 32 * w + (lane & 31);  // 8 producers x 4 waves
  unsigned* const pollG = flagsG + rep * 128 + 32 * w + (lane & 31);
  unsigned* const myfL  = flagsL + rep * 128 + slot * 4 + w;
  unsigned* const myfG  = flagsG + rep * 128 + slot * 4 + w;

  // ---- preloop: u_0 -> ubuf[1]; cpr = c_0 = A*cos(om*1 + u_0); prefetch x_1
  float4 xr0, xr1, xr2, xr3;
  {
    const float* xp = x + (size_t)(b0 + lb) * 64;
    xr0 = *(const float4*)(xp + kg * 8);      xr1 = *(const float4*)(xp + kg * 8 + 4);
    xr2 = *(const float4*)(xp + 32 + kg * 8); xr3 = *(const float4*)(xp + 36 + kg * 8);
    f32x4 au = {0.f, 0.f, 0.f, 0.f};
    au = MFMA16(cvt8(xr0, xr1), wi0, au);
    au = MFMA16(cvt8(xr2, xr3), wi1, au);
    if (kg < 2)
#pragma unroll
      for (int r = 0; r < 4; ++r) ubuf[1][w][lm][kg * 4 + r] = au[r];
  }
  __syncthreads();
#pragma unroll
  for (int j = 0; j < 2; ++j) {
    const int rr = r0 + j;
    const float u0 = ubuf[1][rr >> 4][rr & 15][m] + cB2[j];
    cpr[j] = cA2[j] * __cosf(cOm2[j] * 1.0f + u0);
  }
  {
    const float* xp = x + ((size_t)1 * 64 + b0 + lb) * 64;
    xr0 = *(const float4*)(xp + kg * 8);      xr1 = *(const float4*)(xp + kg * 8 + 4);
    xr2 = *(const float4*)(xp + 32 + kg * 8); xr3 = *(const float4*)(xp + 36 + kg * 8);
  }

  int bR = 0;
  for (int k = 0; k < N_ROUNDS; ++k) {
    const int bW = (bR == 2) ? 0 : bR + 1;
    const int par = k & 1;

    // ---- phase A: u_{k+1} (off the serial chain; all 4 waves, tile nt=w)
    {
      f32x4 au = {0.f, 0.f, 0.f, 0.f};
      au = MFMA16(cvt8(xr0, xr1), wi0, au);
      au = MFMA16(cvt8(xr2, xr3), wi1, au);
      if (kg < 2)
#pragma unroll
        for (int r = 0; r < 4; ++r) ubuf[par][w][lm][kg * 4 + r] = au[r];
    }

    // ---- phase B: alternating poll -- fast leg: sc0 nt (bypass stale L1,
    //      hit shared XCD L2); safe leg: r9-proven agent/LLC atomic load.
    {
      const unsigned tgt = (unsigned)(k + 1);
      for (;;) {
        unsigned v1;
        asm volatile("global_load_dword %0, %1, off sc0 nt\n\ts_waitcnt vmcnt(0)"
                     : "=v"(v1) : "v"(pollL) : "memory");
        if (__all((int)(v1 >= tgt))) break;
        unsigned v2 = __hip_atomic_load(pollG, __ATOMIC_RELAXED, __HIP_MEMORY_SCOPE_AGENT);
        if (__all((int)(v2 >= tgt))) break;
      }
    }

    // ---- phase C: s_k A-frags, K-slice [512w, +512), from XCD L2 (sc0)
    const half_t* ps = St + (size_t)(bR * 8 + rep) * ST_UNIT + lb * NHID + (w * 512 + kg * 8);
    float4 Sr[16];
    asm volatile(
        "global_load_dwordx4 %0, %16, off sc0\n\t"
        "global_load_dwordx4 %1, %16, off offset:64 sc0\n\t"
        "global_load_dwordx4 %2, %16, off offset:128 sc0\n\t"
        "global_load_dwordx4 %3, %16, off offset:192 sc0\n\t"
        "global_load_dwordx4 %4, %16, off offset:256 sc0\n\t"
        "global_load_dwordx4 %5, %16, off offset:320 sc0\n\t"
        "global_load_dwordx4 %6, %16, off offset:384 sc0\n\t"
        "global_load_dwordx4 %7, %16, off offset:448 sc0\n\t"
        "global_load_dwordx4 %8, %16, off offset:512 sc0\n\t"
        "global_load_dwordx4 %9, %16, off offset:576 sc0\n\t"
        "global_load_dwordx4 %10, %16, off offset:640 sc0\n\t"
        "global_load_dwordx4 %11, %16, off offset:704 sc0\n\t"
        "global_load_dwordx4 %12, %16, off offset:768 sc0\n\t"
        "global_load_dwordx4 %13, %16, off offset:832 sc0\n\t"
        "global_load_dwordx4 %14, %16, off offset:896 sc0\n\t"
        "global_load_dwordx4 %15, %16, off offset:960 sc0\n\t"
        "s_waitcnt vmcnt(0)"
        : "=&v"(Sr[0]), "=&v"(Sr[1]), "=&v"(Sr[2]), "=&v"(Sr[3]),
          "=&v"(Sr[4]), "=&v"(Sr[5]), "=&v"(Sr[6]), "=&v"(Sr[7]),
          "=&v"(Sr[8]), "=&v"(Sr[9]), "=&v"(Sr[10]), "=&v"(Sr[11]),
          "=&v"(Sr[12]), "=&v"(Sr[13]), "=&v"(Sr[14]), "=&v"(Sr[15])
        : "v"(ps) : "memory");

    // ---- phase D: y = W * s_k partials (64 MFMA, 4 independent acc chains)
    f32x4 a0 = {0.f,0.f,0.f,0.f}, a1 = {0.f,0.f,0.f,0.f};
    f32x4 a2 = {0.f,0.f,0.f,0.f}, a3 = {0.f,0.f,0.f,0.f};
#pragma unroll
    for (int c = 0; c < 16; ++c) {
      half8 sf = __builtin_bit_cast(half8, Sr[c]);
      a0 = MFMA16(sf, wb[0][c], a0);
      a1 = MFMA16(sf, wb[1][c], a1);
      a2 = MFMA16(sf, wb[2][c], a2);
      a3 = MFMA16(sf, wb[3][c], a3);
    }
    if (kg < 2)
#pragma unroll
      for (int r = 0; r < 4; ++r) {
        ybuf[par][w][0][lm][kg * 4 + r] = a0[r];
        ybuf[par][w][1][lm][kg * 4 + r] = a1[r];
        ybuf[par][w][2][lm][kg * 4 + r] = a2[r];
        ybuf[par][w][3][lm][kg * 4 + r] = a3[r];
      }
    __syncthreads();  // the only barrier per round

    // ---- phase E: s_{k+1} = c_k + y; publish data (sc0), flag (sc0 + agent)
    float s2[2];
#pragma unroll
    for (int j = 0; j < 2; ++j) {
      const int rr = r0 + j;
      const float y = ybuf[par][0][rr >> 4][rr & 15][m] + ybuf[par][1][rr >> 4][rr & 15][m] +
                      ybuf[par][2][rr >> 4][rr & 15][m] + ybuf[par][3][rr >> 4][rr & 15][m];
      s2[j] = cpr[j] + y;
    }
    {
      unsigned h0 = (unsigned)__builtin_bit_cast(unsigned short, (half_t)s2[0]);
      unsigned h1 = (unsigned)__builtin_bit_cast(unsigned short, (half_t)s2[1]);
      unsigned hv = h0 | (h1 << 16);
      const half_t* wp = St + (size_t)(bW * 8 + rep) * ST_UNIT + m * NHID + (n0 + r0);
      asm volatile("global_store_dword %0, %1, off sc0" :: "v"(wp), "v"(hv) : "memory");
      if (k == N_ROUNDS - 1) {
        const half_t* fp2 = StFinal + (size_t)rep * ST_UNIT + m * NHID + (n0 + r0);
        asm volatile("global_store_dword %0, %1, off sc1" :: "v"(fp2), "v"(hv) : "memory");
      }
    }
    asm volatile("s_waitcnt vmcnt(0)" ::: "memory");
    if (lane == 0) {
      unsigned fv = (unsigned)(k + 2);
      asm volatile("global_store_dword %0, %1, off sc0" :: "v"(myfL), "v"(fv) : "memory");
      __hip_atomic_store(myfG, fv, __ATOMIC_RELAXED, __HIP_MEMORY_SCOPE_AGENT);
    }

    // ---- phase F: c_{k+1} = A*cos(om*s_{k+1} + u_{k+1})  (off the chain)
#pragma unroll
    for (int j = 0; j < 2; ++j) {
      const int rr = r0 + j;
      const float u = ubuf[par][rr >> 4][rr & 15][m] + cB2[j];
      cpr[j] = cA2[j] * __cosf(cOm2[j] * s2[j] + u);
    }

    // ---- phase G: x prefetch for u_{k+2}
    {
      int t = k + 2;
      if (t > 511) t = 511;
      const float* xp = x + ((size_t)t * 64 + b0 + lb) * 64;
      xr0 = *(const float4*)(xp + kg * 8);      xr1 = *(const float4*)(xp + kg * 8 + 4);
      xr2 = *(const float4*)(xp + 32 + kg * 8); xr3 = *(const float4*)(xp + 36 + kg * 8);
    }
    bR = bW;
  }
}

__global__ __launch_bounds__(256) void psrnn_readout_kernel(
    const float* __restrict__ Wr_w,     // [64][2048]
    const float* __restrict__ Wr_b,     // [64]
    const half_t* __restrict__ StFinal, // [8][8][2048], LLC copy
    float* __restrict__ out)            // [64][64]
{
  const int tid = threadIdx.x, v = tid >> 6, lane = tid & 63;
  const int lm = lane & 15, kg = lane >> 4, lb = lm & 7;
  const int rep = blockIdx.x;  // 8 blocks
  const half_t* sb = StFinal + (size_t)rep * ST_UNIT;

  f32x4 acc = {0.f, 0.f, 0.f, 0.f};
  for (int cg = 0; cg < 64; ++cg) {
    half8 a = *(const half8*)(sb + (size_t)lb * NHID + cg * 32 + kg * 8);
    const float* p = Wr_w + (size_t)(v * 16 + lm) * NHID + cg * 32 + kg * 8;
    half8 b = cvt8(*(const float4*)p, *(const float4*)(p + 4));
    acc = MFMA16(a, b, acc);
  }
  if (kg < 2)
#pragma unroll
    for (int r = 0; r < 4; ++r)
      out[(rep * 8 + kg * 4 + r) * NOUT + v * 16 + lm] = acc[r] + Wr_b[v * 16 + lm];
}

extern "C" void kernel_launch(void* const* d_in, const int* in_sizes, int n_in,
                              void* d_out, int out_size, void* d_ws, size_t ws_size,
                              hipStream_t stream) {
  const float* x    = (const float*)d_in[0];
  const float* Wi_w = (const float*)d_in[1];
  const float* Wi_b = (const float*)d_in[2];
  const float* Wh_w = (const float*)d_in[3];
  const float* Av   = (const float*)d_in[4];
  const float* Om   = (const float*)d_in[5];
  const float* Wr_w = (const float*)d_in[6];
  const float* Wr_b = (const float*)d_in[7];

  unsigned* flagsL  = (unsigned*)d_ws;
  unsigned* flagsG  = (unsigned*)((char*)d_ws + 8192);
  unsigned* roster  = (unsigned*)((char*)d_ws + 16384);
  half_t*   St      = (half_t*)((char*)d_ws + (1u << 20));
  half_t*   StFinal = (half_t*)((char*)d_ws + (2u << 20));

  psrnn_init_kernel<<<64, 256, 0, stream>>>(flagsL, flagsG, roster, (uint4*)St);
  psrnn_main_kernel<<<256, 256, 61440, stream>>>(x, Wi_w, Wi_b, Wh_w, Av, Om,
                                                 flagsL, flagsG, roster, St, StFinal);
  psrnn_readout_kernel<<<8, 256, 0, stream>>>(Wr_w, Wr_b, StFinal, (float*)d_out);
}

// Round 5
// 1271.478 us; speedup vs baseline: 2.8319x; 1.6044x over previous
//
#include <hip/hip_runtime.h>

// psRNN round 12: r7 base (proven 1211us) + poll-pressure experiment.
// r8-r11 conclusions: (a) flag visibility is hard-floored at LLC RTT on
// gfx950 -- no load flavor below agent scope reliably sees remote flag
// stores (r8 catastrophic, r11 nt-leg neutral); (b) single-XCD reps pay the
// same ~4us chain but amortize 1 step vs r7's 2 (W^2 is the algebraic max);
// (c) same-wave interleave serializes (r10). => r7 structure is the right
// base. Its round (10.15k cy) exceeds the component model (~6k); the gap
// correlates with poll pressure: 1024 waves x continuous agent-scope loads
// of 64 flags = ~10 LLC loads/cy hammering the fabric the publishes must
// transit. This round: ONLY wave 0 of each block polls (all 256 rep flags,
// 4x64 loads + min-reduce) with s_sleep(2) backoff; waves 1-3 spin on an LDS
// ready word (zero fabric traffic). ~6x pressure cut. Everything else
// byte-identical to r7 (W^2 2-step, dual sc0/sc1 publish, 46KB+40KB LDS).
// Predicted: congestion real -> ~950-1000us total, MfmaUtil ~20%; neutral
// -> ~1211 (acquits congestion; next target = publish-drain latency).

typedef _Float16 half_t;
typedef _Float16 half8 __attribute__((ext_vector_type(8)));
typedef float f32x4 __attribute__((ext_vector_type(4)));

#define NHID 2048
#define NOUT 64
#define ST_UNIT 65536   // halfs per (buf,rep): s [0,32768) + c [32768,65536)
#define N_ROUNDS 256

#define MFMA16(A, B, C) __builtin_amdgcn_mfma_f32_16x16x32_f16(A, B, C, 0, 0, 0)

// ws layout (bytes):
//   [0, 4096)       : flags  uint[4][256]  ([rep][slot*4+wave], monotonic)
//   [4096, 4160)    : roster uint[8]       (per-XCD block counter)
//   [1M, 1M+1.5M)   : StA  half[3][4][ST_UNIT]  (sc0 / XCD-L2 copy)
//   [3M, 3M+1.5M)   : StB  half[3][4][ST_UNIT]  (sc1 / LLC copy)
//   [8M, 16M)       : WT16 half[2048][2048]     (W transposed, f16; dead after w2)
//   [16M, 24M)      : W2   half[2048][2048]

__device__ __forceinline__ half8 cvt8(float4 lo, float4 hi) {
  half8 h;
  h[0] = (half_t)lo.x; h[1] = (half_t)lo.y; h[2] = (half_t)lo.z; h[3] = (half_t)lo.w;
  h[4] = (half_t)hi.x; h[5] = (half_t)hi.y; h[6] = (half_t)hi.z; h[7] = (half_t)hi.w;
  return h;
}

__global__ void psrnn_init_kernel(unsigned* flags, unsigned* roster,
                                  uint4* stA, uint4* stB) {
  int g = blockIdx.x * blockDim.x + threadIdx.x;  // 16384 threads
  uint4 v; v.x = 0x3C003C00u; v.y = 0x3C003C00u; v.z = 0x3C003C00u; v.w = 0x3C003C00u;
  const int rep = g >> 12, local = g & 4095;      // buf0 s := fp16 1.0, both copies
  stA[rep * (ST_UNIT / 8) + local] = v;
  stB[rep * (ST_UNIT / 8) + local] = v;
  if (g < 1024) flags[g] = 0;
  else if (g < 1032) roster[g - 1024] = 0;
}

// W (fp32 row-major) -> WT16 (f16, transposed, row-major)
__global__ __launch_bounds__(256) void psrnn_conv_kernel(
    const float* __restrict__ Wh, half_t* __restrict__ WT16) {
  __shared__ float tile[64][65];
  const int bi = blockIdx.x & 31, bj = blockIdx.x >> 5;
  const int rs = threadIdx.x >> 6, c = threadIdx.x & 63;
#pragma unroll
  for (int i = 0; i < 16; ++i) {
    const int row = rs * 16 + i;
    tile[row][c] = Wh[(size_t)(bi * 64 + row) * NHID + bj * 64 + c];
  }
  __syncthreads();
#pragma unroll
  for (int i = 0; i < 16; ++i) {
    const int row = rs * 16 + i;
    WT16[(size_t)(bj * 64 + row) * NHID + bi * 64 + c] = (half_t)tile[c][row];
  }
}

// W2 = f16( f16(W) @ f16(W) ), 128x128 tiles, B-chunk staged in LDS.
__global__ __launch_bounds__(256) void psrnn_w2_kernel(
    const float* __restrict__ Wh, const half_t* __restrict__ WT16,
    half_t* __restrict__ W2) {
  __shared__ half_t Bs[128][40];  // pad 40: 16B-aligned frags, spread banks
  const int bi = blockIdx.x & 15, bj = blockIdx.x >> 4;
  const int tid = threadIdx.x, w = tid >> 6, lane = tid & 63;
  const int lm = lane & 15, kg = lane >> 4;
  const int brow = tid >> 2, bseg = tid & 3;

  f32x4 acc[2][8];
#pragma unroll
  for (int mt = 0; mt < 2; ++mt)
#pragma unroll
    for (int nt = 0; nt < 8; ++nt) acc[mt][nt] = (f32x4){0.f, 0.f, 0.f, 0.f};

  for (int c = 0; c < 64; ++c) {
    __syncthreads();
#pragma unroll
    for (int i = 0; i < 2; ++i) {
      const int row = brow + i * 64;
      *(half8*)&Bs[row][bseg * 8] =
          *(const half8*)(WT16 + (size_t)(bj * 128 + row) * NHID + c * 32 + bseg * 8);
    }
    __syncthreads();
    const float* pa0 = Wh + (size_t)(bi * 128 + w * 32 + lm) * NHID + c * 32 + kg * 8;
    const float* pa1 = pa0 + (size_t)16 * NHID;
    half8 a0 = cvt8(*(const float4*)pa0, *(const float4*)(pa0 + 4));
    half8 a1 = cvt8(*(const float4*)pa1, *(const float4*)(pa1 + 4));
#pragma unroll
    for (int nt = 0; nt < 8; ++nt) {
      half8 b = *(const half8*)&Bs[nt * 16 + lm][kg * 8];
      acc[0][nt] = MFMA16(a0, b, acc[0][nt]);
      acc[1][nt] = MFMA16(a1, b, acc[1][nt]);
    }
  }
#pragma unroll
  for (int mt = 0; mt < 2; ++mt)
#pragma unroll
    for (int nt = 0; nt < 8; ++nt)
#pragma unroll
      for (int r = 0; r < 4; ++r)
        W2[(size_t)(bi * 128 + w * 32 + mt * 16 + kg * 4 + r) * NHID +
           bj * 128 + nt * 16 + lm] = (half_t)acc[mt][nt][r];
}

__global__ __launch_bounds__(256, 1) void psrnn_main_kernel(
    const float* __restrict__ x,      // [512][64][64]
    const float* __restrict__ Wi_w,   // [2048][64]
    const float* __restrict__ Wi_b,   // [2048]
    const float* __restrict__ Wh_w,   // [2048][2048]
    const float* __restrict__ Av,     // [2048]
    const float* __restrict__ Om,     // [2048]
    const half_t* __restrict__ W2,    // [2048][2048] f16
    unsigned* __restrict__ flags,
    unsigned* __restrict__ roster,
    half_t* __restrict__ StA,         // sc0 / XCD-L2 copy
    half_t* __restrict__ StB)         // sc1 / LLC copy
{
  extern __shared__ char lds_force[];        // +40KB dyn: forces 1 block/CU
  __shared__ float ybuf[2][4][2][2][16][18]; // [par][wave][arr][nt][m][n]
  __shared__ float ubuf[2][2][2][16][18];    // [par][t'][nt][m][n]
  __shared__ unsigned slot_sh;
  __shared__ unsigned ready[2];              // [par] LDS poll-release word
  (void)lds_force;

  const int tid = threadIdx.x, w = tid >> 6, lane = tid & 63;
  const int lm = lane & 15, kg = lane >> 4;

  unsigned xcd;
  asm volatile("s_getreg_b32 %0, hwreg(HW_REG_XCC_ID)" : "=s"(xcd));
  const int rep    = (int)(xcd & 3u);
  const int halfId = (int)((xcd >> 2) & 1u);
  if (tid == 0) slot_sh = (unsigned)(halfId * 32) + (atomicAdd(&roster[xcd & 7u], 1u) & 31u);
  if (tid < 2) ready[tid] = 0u;
  __syncthreads();
  const int slot = (int)slot_sh;
  const int n0 = slot * 32, b0 = rep * 16;
  const bool locw = ((w >> 1) == halfId);  // my producers are on my XCD
  const int tpar = w >> 1, ntu = w & 1;    // u-duty: wave -> (timestep, nt)

  // ---- W, W2 B-frags: rows n0+16nt+lm, K = 512w + 32c + kg*8..
  half8 wb[2][16], w2b[2][16];
#pragma unroll
  for (int nt = 0; nt < 2; ++nt)
#pragma unroll
    for (int c = 0; c < 16; ++c) {
      const float* p = Wh_w + (size_t)(n0 + nt * 16 + lm) * NHID + (w * 512 + c * 32 + kg * 8);
      wb[nt][c] = cvt8(*(const float4*)p, *(const float4*)(p + 4));
      w2b[nt][c] = *(const half8*)(W2 + (size_t)(n0 + nt * 16 + lm) * NHID +
                                   (w * 512 + c * 32 + kg * 8));
    }
  half8 wi0, wi1;
  {
    const float* p = Wi_w + (size_t)(n0 + ntu * 16 + lm) * 64 + kg * 8;
    wi0 = cvt8(*(const float4*)p, *(const float4*)(p + 4));
    wi1 = cvt8(*(const float4*)(p + 32), *(const float4*)(p + 36));
  }

  // ---- combiner constants: thread owns (batch m, neurons n0+nt*16+nn)
  const int m = tid >> 4, nn = tid & 15;
  float cA2[2], cOm2[2], cB2[2];
  int off2[2];
#pragma unroll
  for (int nt = 0; nt < 2; ++nt) {
    const int ng = n0 + nt * 16 + nn;
    cA2[nt] = Av[ng]; cOm2[nt] = Om[ng]; cB2[nt] = Wi_b[ng];
    off2[nt] = ((slot * 4 + nt * 2 + (nn >> 3)) * 16 + m) * 8 + (nn & 7);
  }
  float cpr[2];

  unsigned* const myf   = flags + rep * 256 + slot * 4 + w;

  // ---- preloop: u_0 (waves 0,1), publish c_0 to buf0 (both copies), flag=1
  if (w < 2) {
    const float* xp = x + (size_t)(b0 + lm) * 64;
    float4 a0 = *(const float4*)(xp + kg * 8), a1 = *(const float4*)(xp + kg * 8 + 4);
    float4 a2 = *(const float4*)(xp + 32 + kg * 8), a3 = *(const float4*)(xp + 36 + kg * 8);
    f32x4 au = {0.f, 0.f, 0.f, 0.f};
    au = MFMA16(cvt8(a0, a1), wi0, au);
    au = MFMA16(cvt8(a2, a3), wi1, au);
#pragma unroll
    for (int r = 0; r < 4; ++r) ubuf[0][0][ntu][kg * 4 + r][lm] = au[r];
  }
  __syncthreads();
  {
    half_t* cA_ = StA + (size_t)rep * ST_UNIT + 32768;
    half_t* cB_ = StB + (size_t)rep * ST_UNIT + 32768;
#pragma unroll
    for (int nt = 0; nt < 2; ++nt) {
      const float u0 = ubuf[0][0][nt][m][nn] + cB2[nt];
      cpr[nt] = cA2[nt] * __cosf(cOm2[nt] * 1.0f + u0);
      unsigned hv = (unsigned)__builtin_bit_cast(unsigned short, (half_t)cpr[nt]);
      const half_t* pA = cA_ + off2[nt];
      const half_t* pB = cB_ + off2[nt];
      asm volatile("global_store_short %0, %1, off sc0" :: "v"(pA), "v"(hv) : "memory");
      asm volatile("global_store_short %0, %1, off sc1" :: "v"(pB), "v"(hv) : "memory");
    }
    asm volatile("s_waitcnt vmcnt(0)" ::: "memory");
    if (lane == 0)
      __hip_atomic_store(myf, 1u, __ATOMIC_RELAXED, __HIP_MEMORY_SCOPE_AGENT);
  }
  float4 xr0, xr1, xr2, xr3;
  {
    const float* xp = x + ((size_t)(1 + tpar) * 64 + b0 + lm) * 64;
    xr0 = *(const float4*)(xp + kg * 8);  xr1 = *(const float4*)(xp + kg * 8 + 4);
    xr2 = *(const float4*)(xp + 32 + kg * 8); xr3 = *(const float4*)(xp + 36 + kg * 8);
  }

  int bR = 0;
  for (int k = 0; k < N_ROUNDS; ++k) {
    const int bW = (bR == 2) ? 0 : bR + 1;
    const int par = k & 1;

    // ---- phase A: u for t1=2k+1 (waves 0,1) / t2=2k+2 (waves 2,3)
    {
      f32x4 au = {0.f, 0.f, 0.f, 0.f};
      au = MFMA16(cvt8(xr0, xr1), wi0, au);
      au = MFMA16(cvt8(xr2, xr3), wi1, au);
#pragma unroll
      for (int r = 0; r < 4; ++r) ubuf[par][tpar][ntu][kg * 4 + r][lm] = au[r];
    }

    // ---- phase B: single-poller wave (w==0) checks ALL 256 rep flags with
    //      s_sleep backoff; waves 1-3 spin on LDS ready word (no fabric
    //      traffic). ~6x poll-pressure cut vs r7's 1024 polling waves.
    {
      const unsigned tgt = (unsigned)(k + 1);
      if (w == 0) {
        unsigned* fb = flags + rep * 256 + lane;
        for (;;) {
          unsigned v0 = __hip_atomic_load(fb,       __ATOMIC_RELAXED, __HIP_MEMORY_SCOPE_AGENT);
          unsigned v1 = __hip_atomic_load(fb + 64,  __ATOMIC_RELAXED, __HIP_MEMORY_SCOPE_AGENT);
          unsigned v2 = __hip_atomic_load(fb + 128, __ATOMIC_RELAXED, __HIP_MEMORY_SCOPE_AGENT);
          unsigned v3 = __hip_atomic_load(fb + 192, __ATOMIC_RELAXED, __HIP_MEMORY_SCOPE_AGENT);
          unsigned m01 = v0 < v1 ? v0 : v1;
          unsigned m23 = v2 < v3 ? v2 : v3;
          unsigned mn  = m01 < m23 ? m01 : m23;
          if (__all((int)(mn >= tgt))) break;
          __builtin_amdgcn_s_sleep(2);
        }
        if (lane == 0) ((volatile unsigned*)ready)[par] = tgt;
      } else {
        while (((volatile unsigned*)ready)[par] < tgt) { }
      }
    }

    // ---- phase C: (s,c) frags of K-slice [512w,+512); local half from XCD L2
    //      (sc0), cross half from LLC (sc1)
    const half_t* rb = (locw ? StA : StB) + (size_t)(bR * 4 + rep) * ST_UNIT;
    const half_t* ps0 = rb + w * 8192 + kg * 128 + lm * 8;
    const half_t* ps1 = ps0 + 2048;
    const half_t* ps2 = ps0 + 4096;
    const half_t* ps3 = ps0 + 6144;
    const half_t* pc0 = ps0 + 32768;
    const half_t* pc1 = ps1 + 32768;
    const half_t* pc2 = ps2 + 32768;
    const half_t* pc3 = ps3 + 32768;
    float4 Sr[16], Cr[16];
#define LOADS(SC)                                                         \
    asm volatile(                                                         \
        "global_load_dwordx4 %0, %32, off " SC "\n\t"                     \
        "global_load_dwordx4 %1, %32, off offset:1024 " SC "\n\t"         \
        "global_load_dwordx4 %2, %32, off offset:2048 " SC "\n\t"         \
        "global_load_dwordx4 %3, %32, off offset:3072 " SC "\n\t"         \
        "global_load_dwordx4 %4, %33, off " SC "\n\t"                     \
        "global_load_dwordx4 %5, %33, off offset:1024 " SC "\n\t"         \
        "global_load_dwordx4 %6, %33, off offset:2048 " SC "\n\t"         \
        "global_load_dwordx4 %7, %33, off offset:3072 " SC "\n\t"         \
        "global_load_dwordx4 %8, %34, off " SC "\n\t"                     \
        "global_load_dwordx4 %9, %34, off offset:1024 " SC "\n\t"         \
        "global_load_dwordx4 %10, %34, off offset:2048 " SC "\n\t"        \
        "global_load_dwordx4 %11, %34, off offset:3072 " SC "\n\t"        \
        "global_load_dwordx4 %12, %35, off " SC "\n\t"                    \
        "global_load_dwordx4 %13, %35, off offset:1024 " SC "\n\t"        \
        "global_load_dwordx4 %14, %35, off offset:2048 " SC "\n\t"        \
        "global_load_dwordx4 %15, %35, off offset:3072 " SC "\n\t"        \
        "global_load_dwordx4 %16, %36, off " SC "\n\t"                    \
        "global_load_dwordx4 %17, %36, off offset:1024 " SC "\n\t"        \
        "global_load_dwordx4 %18, %36, off offset:2048 " SC "\n\t"        \
        "global_load_dwordx4 %19, %36, off offset:3072 " SC "\n\t"        \
        "global_load_dwordx4 %20, %37, off " SC "\n\t"                    \
        "global_load_dwordx4 %21, %37, off offset:1024 " SC "\n\t"        \
        "global_load_dwordx4 %22, %37, off offset:2048 " SC "\n\t"        \
        "global_load_dwordx4 %23, %37, off offset:3072 " SC "\n\t"        \
        "global_load_dwordx4 %24, %38, off " SC "\n\t"                    \
        "global_load_dwordx4 %25, %38, off offset:1024 " SC "\n\t"        \
        "global_load_dwordx4 %26, %38, off offset:2048 " SC "\n\t"        \
        "global_load_dwordx4 %27, %38, off offset:3072 " SC "\n\t"        \
        "global_load_dwordx4 %28, %39, off " SC "\n\t"                    \
        "global_load_dwordx4 %29, %39, off offset:1024 " SC "\n\t"        \
        "global_load_dwordx4 %30, %39, off offset:2048 " SC "\n\t"        \
        "global_load_dwordx4 %31, %39, off offset:3072 " SC "\n\t"        \
        "s_waitcnt vmcnt(0)"                                              \
        : "=&v"(Sr[0]), "=&v"(Sr[1]), "=&v"(Sr[2]), "=&v"(Sr[3]),         \
          "=&v"(Sr[4]), "=&v"(Sr[5]), "=&v"(Sr[6]), "=&v"(Sr[7]),         \
          "=&v"(Sr[8]), "=&v"(Sr[9]), "=&v"(Sr[10]), "=&v"(Sr[11]),       \
          "=&v"(Sr[12]), "=&v"(Sr[13]), "=&v"(Sr[14]), "=&v"(Sr[15]),     \
          "=&v"(Cr[0]), "=&v"(Cr[1]), "=&v"(Cr[2]), "=&v"(Cr[3]),         \
          "=&v"(Cr[4]), "=&v"(Cr[5]), "=&v"(Cr[6]), "=&v"(Cr[7]),         \
          "=&v"(Cr[8]), "=&v"(Cr[9]), "=&v"(Cr[10]), "=&v"(Cr[11]),       \
          "=&v"(Cr[12]), "=&v"(Cr[13]), "=&v"(Cr[14]), "=&v"(Cr[15])      \
        : "v"(ps0), "v"(ps1), "v"(ps2), "v"(ps3),                         \
          "v"(pc0), "v"(pc1), "v"(pc2), "v"(pc3)                          \
        : "memory")
    if (locw) { LOADS("sc0"); } else { LOADS("sc1"); }
#undef LOADS

    // ---- phase D: y1 = W*s ; y23 = W*c + W^2*s   (96 MFMA)
    f32x4 y1a0 = {0.f,0.f,0.f,0.f}, y1a1 = {0.f,0.f,0.f,0.f};
    f32x4 y23a0 = {0.f,0.f,0.f,0.f}, y23a1 = {0.f,0.f,0.f,0.f};
#pragma unroll
    for (int c = 0; c < 16; ++c) {
      half8 sf = __builtin_bit_cast(half8, Sr[c]);
      half8 cf = __builtin_bit_cast(half8, Cr[c]);
      y1a0 = MFMA16(sf, wb[0][c], y1a0);
      y1a1 = MFMA16(sf, wb[1][c], y1a1);
      y23a0 = MFMA16(cf, wb[0][c], y23a0);
      y23a1 = MFMA16(cf, wb[1][c], y23a1);
      y23a0 = MFMA16(sf, w2b[0][c], y23a0);
      y23a1 = MFMA16(sf, w2b[1][c], y23a1);
    }
#pragma unroll
    for (int r = 0; r < 4; ++r) {
      ybuf[par][w][0][0][kg * 4 + r][lm] = y1a0[r];
      ybuf[par][w][0][1][kg * 4 + r][lm] = y1a1[r];
      ybuf[par][w][1][0][kg * 4 + r][lm] = y23a0[r];
      ybuf[par][w][1][1][kg * 4 + r][lm] = y23a1[r];
    }
    __syncthreads();  // the only barrier per round

    // ---- phase E: combine two steps, dual-publish (s,c), flag
    half_t* wBA = StA + (size_t)(bW * 4 + rep) * ST_UNIT;
    half_t* wBB = StB + (size_t)(bW * 4 + rep) * ST_UNIT;
#pragma unroll
    for (int nt = 0; nt < 2; ++nt) {
      const float y1v = ybuf[par][0][0][nt][m][nn] + ybuf[par][1][0][nt][m][nn] +
                        ybuf[par][2][0][nt][m][nn] + ybuf[par][3][0][nt][m][nn];
      const float y23v = ybuf[par][0][1][nt][m][nn] + ybuf[par][1][1][nt][m][nn] +
                         ybuf[par][2][1][nt][m][nn] + ybuf[par][3][1][nt][m][nn];
      const float u1 = ubuf[par][0][nt][m][nn] + cB2[nt];
      const float u2 = ubuf[par][1][nt][m][nn] + cB2[nt];
      const float s1 = cpr[nt] + y1v;
      const float c1 = cA2[nt] * __cosf(cOm2[nt] * s1 + u1);
      const float s2 = c1 + y23v;
      const float c2 = cA2[nt] * __cosf(cOm2[nt] * s2 + u2);
      cpr[nt] = c2;
      unsigned hs = (unsigned)__builtin_bit_cast(unsigned short, (half_t)s2);
      unsigned hc = (unsigned)__builtin_bit_cast(unsigned short, (half_t)c2);
      const half_t* sA = wBA + off2[nt];
      const half_t* sB = wBB + off2[nt];
      const half_t* cAp = wBA + 32768 + off2[nt];
      const half_t* cBp = wBB + 32768 + off2[nt];
      asm volatile("global_store_short %0, %1, off sc0" :: "v"(sA), "v"(hs) : "memory");
      asm volatile("global_store_short %0, %1, off sc1" :: "v"(sB), "v"(hs) : "memory");
      asm volatile("global_store_short %0, %1, off sc0" :: "v"(cAp), "v"(hc) : "memory");
      asm volatile("global_store_short %0, %1, off sc1" :: "v"(cBp), "v"(hc) : "memory");
    }
    asm volatile("s_waitcnt vmcnt(0)" ::: "memory");
    if (lane == 0)
      __hip_atomic_store(myf, (unsigned)(k + 2), __ATOMIC_RELAXED, __HIP_MEMORY_SCOPE_AGENT);

    // ---- phase G: x prefetch for round k+1 (off the serial chain)
    {
      int t = 2 * k + 3 + tpar;
      if (t > 511) t = 511;
      const float* xp = x + ((size_t)t * 64 + b0 + lm) * 64;
      xr0 = *(const float4*)(xp + kg * 8);  xr1 = *(const float4*)(xp + kg * 8 + 4);
      xr2 = *(const float4*)(xp + 32 + kg * 8); xr3 = *(const float4*)(xp + 36 + kg * 8);
    }
    bR = bW;
  }
}

__global__ __launch_bounds__(256) void psrnn_readout_kernel(
    const float* __restrict__ Wr_w,   // [64][2048]
    const float* __restrict__ Wr_b,   // [64]
    const half_t* __restrict__ StB,   // LLC copy; final state in buf 1
    float* __restrict__ out)          // [64][64]
{
  const int tid = threadIdx.x, v = tid >> 6, lane = tid & 63;
  const int lm = lane & 15, kg = lane >> 4;
  const int rep = blockIdx.x;  // 4 blocks
  const half_t* sb = StB + (size_t)(1 * 4 + rep) * ST_UNIT;  // buf (255+1)%3 = 1

  f32x4 acc = {0.f, 0.f, 0.f, 0.f};
  for (int cg = 0; cg < 64; ++cg) {
    half8 a = *(const half8*)(sb + (size_t)cg * 512 + kg * 128 + lm * 8);
    const float* p = Wr_w + (size_t)(v * 16 + lm) * NHID + cg * 32 + kg * 8;
    half8 b = cvt8(*(const float4*)p, *(const float4*)(p + 4));
    acc = MFMA16(a, b, acc);
  }
#pragma unroll
  for (int r = 0; r < 4; ++r) {
    const int bidx = rep * 16 + kg * 4 + r;
    out[bidx * NOUT + v * 16 + lm] = acc[r] + Wr_b[v * 16 + lm];
  }
}

extern "C" void kernel_launch(void* const* d_in, const int* in_sizes, int n_in,
                              void* d_out, int out_size, void* d_ws, size_t ws_size,
                              hipStream_t stream) {
  const float* x    = (const float*)d_in[0];
  const float* Wi_w = (const float*)d_in[1];
  const float* Wi_b = (const float*)d_in[2];
  const float* Wh_w = (const float*)d_in[3];
  const float* Av   = (const float*)d_in[4];
  const float* Om   = (const float*)d_in[5];
  const float* Wr_w = (const float*)d_in[6];
  const float* Wr_b = (const float*)d_in[7];

  unsigned* flags  = (unsigned*)d_ws;
  unsigned* roster = (unsigned*)((char*)d_ws + 4096);
  half_t*   StA    = (half_t*)((char*)d_ws + (1u << 20));
  half_t*   StB    = (half_t*)((char*)d_ws + (3u << 20));
  half_t*   WT16   = (half_t*)((char*)d_ws + (8u << 20));
  half_t*   W2     = (half_t*)((char*)d_ws + (16u << 20));

  psrnn_conv_kernel<<<1024, 256, 0, stream>>>(Wh_w, WT16);
  psrnn_w2_kernel<<<256, 256, 0, stream>>>(Wh_w, WT16, W2);
  psrnn_init_kernel<<<64, 256, 0, stream>>>(flags, roster, (uint4*)StA, (uint4*)StB);
  psrnn_main_kernel<<<256, 256, 40960, stream>>>(x, Wi_w, Wi_b, Wh_w, Av, Om, W2,
                                                 flags, roster, StA, StB);
  psrnn_readout_kernel<<<4, 256, 0, stream>>>(Wr_w, Wr_b, StB, (float*)d_out);
}